// Round 4
// baseline (193.360 us; speedup 1.0000x reference)
//
#include <hip/hip_runtime.h>

#define NUM_BINS 256
#define HW4 65536                  // 512*512/4 float4 per plane
#define NGROUPS 6                  // {img1,img2} x {c0,c1,c2}
#define BLOCKS_PER_GROUP 256       // 16 blocks per plane x 16 planes
#define THREADS 64                 // one wave per block
#define F4_PER_BLOCK 4096
#define ITERS (F4_PER_BLOCK / THREADS)   // 64

// ---------------------------------------------------------------------------
// Kernel 1: per-lane private u16 sub-histograms in LDS (no atomics in the
// hot loop). hist16[bin][lane]: halfword addr = bin*64+lane -> bank = lane/2,
// 2 lanes/bank = conflict-free. Lane-private => plain read-modify-write.
// ---------------------------------------------------------------------------
__global__ __launch_bounds__(THREADS) void hist_kernel(
    const float* __restrict__ img1,
    const float* __restrict__ img2,
    unsigned int* __restrict__ ghist /* [6][256] */) {

    __shared__ unsigned short h16[NUM_BINS * 64];   // 32 KB

    const int lane = threadIdx.x;

    // zero 32 KB: 2048 uint4 / 64 lanes = 32 per lane
    uint4* z = (uint4*)h16;
    #pragma unroll
    for (int i = 0; i < 32; ++i)
        z[i * THREADS + lane] = make_uint4(0u, 0u, 0u, 0u);
    __syncthreads();

    const int gid = blockIdx.x;
    const int group = gid >> 8;                 // 0..5
    const int blk = gid & (BLOCKS_PER_GROUP - 1);
    const int im = (group >= 3) ? 1 : 0;
    const int c = group - im * 3;
    const int b = blk >> 4;                     // batch plane
    const int joff = (blk & 15) * F4_PER_BLOCK; // within-plane float4 offset
    const float4* __restrict__ src =
        (const float4*)(im ? img2 : img1) + (size_t)(b * 3 + c) * HW4 + joff + lane;

    #pragma unroll 4
    for (int it = 0; it < ITERS; ++it) {
        const float4 v = src[it * THREADS];     // coalesced 1 KB / wave-instr
        const float xs[4] = {v.x, v.y, v.z, v.w};
        #pragma unroll
        for (int e = 0; e < 4; ++e) {
            const float x = xs[e];
            // torch.histc semantics: ignore outside [0,1]; x==1 -> last bin
            if (x >= 0.0f && x <= 1.0f) {
                int bi = (int)(x * 256.0f);     // trunc == floor (x >= 0)
                bi = bi > (NUM_BINS - 1) ? (NUM_BINS - 1) : bi;
                const int idx = (bi << 6) | lane;        // lane-private slot
                h16[idx] = (unsigned short)(h16[idx] + 1u);
            }
        }
    }
    __syncthreads();

    // reduce: lane owns bins {lane, 64+lane, 128+lane, 192+lane}
    #pragma unroll
    for (int q = 0; q < 4; ++q) {
        const int bin = (q << 6) | lane;
        const uint4* row = (const uint4*)&h16[bin << 6];   // 8 uint4 = 64 u16
        unsigned int s = 0;
        #pragma unroll
        for (int cc = 0; cc < 8; ++cc) {
            // rotate chunk index by lane to spread banks on the row reads
            const uint4 w = row[(cc + lane) & 7];
            s += (w.x & 0xffffu) + (w.x >> 16) + (w.y & 0xffffu) + (w.y >> 16)
               + (w.z & 0xffffu) + (w.z >> 16) + (w.w & 0xffffu) + (w.w >> 16);
        }
        if (s) atomicAdd(&ghist[group * NUM_BINS + bin], s);
    }
}

// ---------------------------------------------------------------------------
// Kernel 2: normalize, cumsum, sum |cdf1 - cdf2|, /3. One block, 256 threads.
// ---------------------------------------------------------------------------
__global__ __launch_bounds__(NUM_BINS) void finalize_kernel(
    const unsigned int* __restrict__ hist, float* __restrict__ out) {

    __shared__ float b1[NUM_BINS];
    __shared__ float b2[NUM_BINS];
    __shared__ float red[NUM_BINS / 64];

    const int t = threadIdx.x;
    float acc = 0.0f;

    for (int c = 0; c < 3; ++c) {
        b1[t] = (float)hist[c * NUM_BINS + t];
        b2[t] = (float)hist[(3 + c) * NUM_BINS + t];
        __syncthreads();
        // Hillis-Steele inclusive scan, 8 steps
        for (int off = 1; off < NUM_BINS; off <<= 1) {
            float a1 = 0.0f, a2 = 0.0f;
            if (t >= off) { a1 = b1[t - off]; a2 = b2[t - off]; }
            __syncthreads();
            b1[t] += a1;
            b2[t] += a2;
            __syncthreads();
        }
        acc += fabsf(b1[t] / b1[NUM_BINS - 1] - b2[t] / b2[NUM_BINS - 1]);
        __syncthreads();                  // protect b1/b2 reuse next channel
    }

    #pragma unroll
    for (int off = 32; off > 0; off >>= 1)
        acc += __shfl_down(acc, off, 64);
    if ((t & 63) == 0) red[t >> 6] = acc;
    __syncthreads();
    if (t == 0)
        out[0] = (red[0] + red[1] + red[2] + red[3]) * (1.0f / 3.0f);
}

// ---------------------------------------------------------------------------
extern "C" void kernel_launch(void* const* d_in, const int* in_sizes, int n_in,
                              void* d_out, int out_size, void* d_ws,
                              size_t ws_size, hipStream_t stream) {
    const float* img1 = (const float*)d_in[0];
    const float* img2 = (const float*)d_in[1];
    float* out = (float*)d_out;
    unsigned int* hist = (unsigned int*)d_ws;   // [6][256] uint32

    // d_ws is poisoned to 0xAA before every launch -> zero hist every call
    hipMemsetAsync(hist, 0, NGROUPS * NUM_BINS * sizeof(unsigned int), stream);

    hist_kernel<<<NGROUPS * BLOCKS_PER_GROUP, THREADS, 0, stream>>>(img1, img2,
                                                                    hist);
    finalize_kernel<<<1, NUM_BINS, 0, stream>>>(hist, out);
}

// Round 7
// 140.759 us; speedup vs baseline: 1.3737x; 1.3737x over previous
//
#include <hip/hip_runtime.h>

#define NUM_BINS 256
#define HW4 65536                  // float4 per plane (512*512/4)
#define NGROUPS 6                  // {img1,img2} x {c0,c1,c2}
#define BPG 512                    // blocks per group
#define GRID (NGROUPS * BPG)       // 3072
#define THREADS 64                 // one wave per block
#define F4_PER_BLOCK 2048          // 1048576 / 512
#define BATCHES 16                 // 2 float4 (8 elems) per lane per batch
#define ROWS_ALLOC 272             // 257 rows (256 bins + dummy) padded

// ---------------------------------------------------------------------------
// Kernel 1: per-lane private u8 sub-histograms, batch-8 + in-register dedup.
// h8[row][lane]; row 256 = dummy sink for out-of-range values (never read).
// 8 independent ds_read_u8 in flight per batch -> 8x less exposed latency;
// 16.4 KB LDS -> 9 blocks/CU (vs 5 at u16).
// ---------------------------------------------------------------------------
__global__ __launch_bounds__(THREADS) void hist_kernel(
    const float* __restrict__ img1,
    const float* __restrict__ img2,
    unsigned int* __restrict__ ghist /* [6][256] */) {

    __shared__ unsigned char h8[ROWS_ALLOC * 64];   // 17408 B

    const int lane = threadIdx.x;

    // zero: 1088 uint4 / 64 lanes = 17 per lane
    uint4* z = (uint4*)h8;
    #pragma unroll
    for (int i = 0; i < 17; ++i)
        z[i * THREADS + lane] = make_uint4(0u, 0u, 0u, 0u);
    __syncthreads();

    const int gid = blockIdx.x;
    const int group = gid >> 9;                 // 0..5
    const int blk = gid & (BPG - 1);
    const int im = (group >= 3) ? 1 : 0;
    const int c = group - im * 3;
    const int b = blk >> 5;                     // batch plane (32 blocks/plane)
    const int joff = (blk & 31) * F4_PER_BLOCK; // within-plane float4 offset
    const float4* __restrict__ src =
        (const float4*)(im ? img2 : img1) + (size_t)(b * 3 + c) * HW4 + joff + lane;

    // software pipeline: prefetch next batch's 2 float4 while processing
    float4 va = src[0];
    float4 vb = src[THREADS];

    for (int it = 0; it < BATCHES; ++it) {
        float4 na, nb;
        if (it + 1 < BATCHES) {
            na = src[(it + 1) * 2 * THREADS];
            nb = src[(it + 1) * 2 * THREADS + THREADS];
        }

        const float xs[8] = {va.x, va.y, va.z, va.w, vb.x, vb.y, vb.z, vb.w};
        int row[8];
        #pragma unroll
        for (int e = 0; e < 8; ++e) {
            const float x = xs[e];
            // torch.histc: ignore outside [0,1]; x==1 -> last bin
            int bi = (int)(x * 256.0f);            // trunc == floor (x >= 0)
            bi = bi > (NUM_BINS - 1) ? (NUM_BINS - 1) : bi;
            row[e] = (x >= 0.0f && x <= 1.0f) ? bi : 256;   // 256 = dummy sink
        }

        // in-register dedup: first occurrence absorbs duplicates' counts
        unsigned inc[8], dead[8];
        #pragma unroll
        for (int e = 0; e < 8; ++e) { inc[e] = 1u; dead[e] = 0u; }
        #pragma unroll
        for (int i = 0; i < 8; ++i)
            #pragma unroll
            for (int j = i + 1; j < 8; ++j) {
                const unsigned e = (row[i] == row[j]) ? 1u : 0u;
                inc[i] += e;
                dead[j] |= e;
            }

        // 8 independent reads (all outstanding), then guarded writes
        unsigned v[8];
        #pragma unroll
        for (int e = 0; e < 8; ++e)
            v[e] = h8[(row[e] << 6) | lane];
        #pragma unroll
        for (int e = 0; e < 8; ++e)
            if (!dead[e])
                h8[(row[e] << 6) | lane] = (unsigned char)(v[e] + inc[e]);

        va = na; vb = nb;
    }
    __syncthreads();

    // flush: lane owns bins {lane, 64+lane, 128+lane, 192+lane}
    #pragma unroll
    for (int q = 0; q < 4; ++q) {
        const int bin = (q << 6) | lane;
        const unsigned* rowp = (const unsigned*)&h8[bin << 6];  // 16 words
        unsigned s = 0;
        #pragma unroll
        for (int w = 0; w < 16; ++w) {
            const unsigned x = rowp[(w + (lane >> 1)) & 15];    // spread banks
            s += (x & 0xffu) + ((x >> 8) & 0xffu) + ((x >> 16) & 0xffu)
               + (x >> 24);
        }
        if (s) atomicAdd(&ghist[group * NUM_BINS + bin], s);
    }
}

// ---------------------------------------------------------------------------
// Kernel 2: normalize, cumsum, sum |cdf1 - cdf2|, /3. One block, 256 threads.
// ---------------------------------------------------------------------------
__global__ __launch_bounds__(NUM_BINS) void finalize_kernel(
    const unsigned int* __restrict__ hist, float* __restrict__ out) {

    __shared__ float b1[NUM_BINS];
    __shared__ float b2[NUM_BINS];
    __shared__ float red[NUM_BINS / 64];

    const int t = threadIdx.x;
    float acc = 0.0f;

    for (int c = 0; c < 3; ++c) {
        b1[t] = (float)hist[c * NUM_BINS + t];
        b2[t] = (float)hist[(3 + c) * NUM_BINS + t];
        __syncthreads();
        // Hillis-Steele inclusive scan, 8 steps
        for (int off = 1; off < NUM_BINS; off <<= 1) {
            float a1 = 0.0f, a2 = 0.0f;
            if (t >= off) { a1 = b1[t - off]; a2 = b2[t - off]; }
            __syncthreads();
            b1[t] += a1;
            b2[t] += a2;
            __syncthreads();
        }
        acc += fabsf(b1[t] / b1[NUM_BINS - 1] - b2[t] / b2[NUM_BINS - 1]);
        __syncthreads();                  // protect b1/b2 reuse next channel
    }

    #pragma unroll
    for (int off = 32; off > 0; off >>= 1)
        acc += __shfl_down(acc, off, 64);
    if ((t & 63) == 0) red[t >> 6] = acc;
    __syncthreads();
    if (t == 0)
        out[0] = (red[0] + red[1] + red[2] + red[3]) * (1.0f / 3.0f);
}

// ---------------------------------------------------------------------------
extern "C" void kernel_launch(void* const* d_in, const int* in_sizes, int n_in,
                              void* d_out, int out_size, void* d_ws,
                              size_t ws_size, hipStream_t stream) {
    const float* img1 = (const float*)d_in[0];
    const float* img2 = (const float*)d_in[1];
    float* out = (float*)d_out;
    unsigned int* hist = (unsigned int*)d_ws;   // [6][256] uint32

    // d_ws is poisoned to 0xAA before every launch -> zero hist every call
    hipMemsetAsync(hist, 0, NGROUPS * NUM_BINS * sizeof(unsigned int), stream);

    hist_kernel<<<GRID, THREADS, 0, stream>>>(img1, img2, hist);
    finalize_kernel<<<1, NUM_BINS, 0, stream>>>(hist, out);
}